// Round 5
// baseline (102.763 us; speedup 1.0000x reference)
//
#include <hip/hip_runtime.h>

#define RES 1024
#define NV 8
#define HW (RES * RES)

typedef float f32x4 __attribute__((ext_vector_type(4)));

// ---------------------------------------------------------------- bbox + params (fused)
// 256 blocks per view; each block reduces its 1024-quad chunk into one int4 partial.
// The LAST block of each view (atomic counter) reduces all 256 partials and
// computes params + kc_new — no separate params launch.
__global__ __launch_bounds__(256) void bbox_params_kernel(const float* __restrict__ masks,
                                                          const float* __restrict__ kc,
                                                          int4* __restrict__ part,
                                                          int* __restrict__ cnt,
                                                          float* __restrict__ params,
                                                          float* __restrict__ kc_out) {
    const int v = blockIdx.y;
    const int b = blockIdx.x;                 // 0..255
    const float4* m = (const float4*)(masks + (size_t)v * HW);
    int lminy = 1 << 30, lmaxy = -1, lminx = 1 << 30, lmaxx = -1;
    int base = b * 1024 + threadIdx.x;
#pragma unroll
    for (int i = 0; i < 4; ++i) {
        int q = base + i * 256;
        float4 f = m[q];
        bool a = f.x > 0.5f, bb = f.y > 0.5f, c = f.z > 0.5f, d = f.w > 0.5f;
        if (a | bb | c | d) {
            int lin = q << 2;
            int y = lin >> 10;
            int x = lin & (RES - 1);
            lminy = min(lminy, y); lmaxy = max(lmaxy, y);
            if (a)  { lminx = min(lminx, x);     lmaxx = max(lmaxx, x);     }
            if (bb) { lminx = min(lminx, x + 1); lmaxx = max(lmaxx, x + 1); }
            if (c)  { lminx = min(lminx, x + 2); lmaxx = max(lmaxx, x + 2); }
            if (d)  { lminx = min(lminx, x + 3); lmaxx = max(lmaxx, x + 3); }
        }
    }
    __shared__ int s[4];
    __shared__ int slast;
    if (threadIdx.x == 0) { s[0] = 1 << 30; s[1] = -1; s[2] = 1 << 30; s[3] = -1; }
    __syncthreads();
    if (lmaxy >= 0) {
        atomicMin(&s[0], lminy); atomicMax(&s[1], lmaxy);
        atomicMin(&s[2], lminx); atomicMax(&s[3], lmaxx);
    }
    __syncthreads();
    if (threadIdx.x == 0) {
        part[v * 256 + b] = make_int4(s[0], s[1], s[2], s[3]);
        __threadfence();                       // publish partial before counting
        slast = (atomicAdd(&cnt[v], 1) == 255);
    }
    __syncthreads();
    if (!slast || threadIdx.x >= 64) return;

    // last block of this view: 64-lane reduce of 256 partials
    __threadfence();                           // order counter read before partial loads
    const int lane = threadIdx.x;
    int bminh = 1 << 30, bmaxh = -1, bminw = 1 << 30, bmaxw = -1;
#pragma unroll
    for (int i = 0; i < 4; ++i) {
        int4 p = part[v * 256 + lane + 64 * i];
        bminh = min(bminh, p.x); bmaxh = max(bmaxh, p.y);
        bminw = min(bminw, p.z); bmaxw = max(bmaxw, p.w);
    }
#pragma unroll
    for (int o = 32; o; o >>= 1) {
        bminh = min(bminh, __shfl_down(bminh, o));
        bmaxh = max(bmaxh, __shfl_down(bmaxh, o));
        bminw = min(bminw, __shfl_down(bminw, o));
        bmaxw = max(bmaxw, __shfl_down(bmaxw, o));
    }
    if (lane != 0) return;
    if (bmaxh < 0) { bminh = 0; bmaxh = RES - 1; }   // empty-mask fallback == ref semantics
    if (bmaxw < 0) { bminw = 0; bmaxw = RES - 1; }
    float mh = (float)min(max(bminh - 100, 0), RES - 1);
    float Mh = (float)min(max(bmaxh + 100, 0), RES - 1);
    float mw = (float)min(max(bminw - 100, 0), RES - 1);
    float Mw = (float)min(max(bmaxw + 100, 0), RES - 1);
    float hn = Mh - mh, wn = Mw - mw;
    bool vert = (hn >= wn);
    float ohf = vert ? 1024.0f : floorf(__fdiv_rn(__fmul_rn(hn, 1024.0f), wn));
    float owf = vert ? floorf(__fdiv_rn(__fmul_rn(wn, 1024.0f), hn)) : 1024.0f;
    float pt = floorf(__fmul_rn(1024.0f - ohf, 0.5f));
    float pl = floorf(__fmul_rn(1024.0f - owf, 0.5f));
    float* P = params + v * 16;
    P[0] = mh; P[1] = mw; P[2] = hn; P[3] = wn;
    P[4] = ohf; P[5] = owf; P[6] = pt; P[7] = pl;
    P[8] = __fdiv_rn(wn, owf);
    P[9] = __fdiv_rn(hn, ohf);

    // kc_new = R @ (A @ kc),  R = [[0,1,0],[-1,0,1024],[0,0,1]] (ROT_DEG==1)
    float axk = __fdiv_rn(owf, wn), ayk = __fdiv_rn(ohf, hn);
    float t0 = pl - mw * axk;
    float t1 = pt - mh * ayk;
    const float* K = kc + v * 9;
    float M0[3], M1[3], M2[3];
    for (int k = 0; k < 3; ++k) {
        M0[k] = axk * K[k]     + t0 * K[6 + k];
        M1[k] = ayk * K[3 + k] + t1 * K[6 + k];
        M2[k] = K[6 + k];
    }
    float* O = kc_out + v * 9;
    for (int k = 0; k < 3; ++k) {
        O[k]     = M1[k];
        O[3 + k] = -M0[k] + 1024.0f * M2[k];
        O[6 + k] = M2[k];
    }
}

// ---------------------------------------------------------------- resample + rot90
// Pre-rotation sample image S[v,c,y,x]; output out[i,j] = S[j, RES-1-i].
// Block computes a 32x32 S-tile; 4 plane tiles staged in LDS; ONE barrier;
// rotated write as float4 nontemporal stores.
__global__ __launch_bounds__(256) void resample_kernel(const float* __restrict__ rgbs,
                                                       const float* __restrict__ masks,
                                                       const float* __restrict__ params,
                                                       float* __restrict__ out) {
    const int v = blockIdx.z;
    const int x0b = blockIdx.x * 32;
    const int y0b = blockIdx.y * 32;
    const int t = threadIdx.x;        // 0..255
    const int tx = t & 31;            // x within S tile
    const int ty = t >> 5;            // 0..7
    const int il = t >> 3;            // output row within tile (epilogue)
    const int q  = t & 7;             // float4 group (epilogue)
    const int ibase = 992 - x0b;      // RES-1-(x0b+31)

    const float* P = params + v * 16;
    const float mh = P[0], mw = P[1], hn = P[2], wn = P[3];
    const float ohf = P[4], owf = P[5], pt = P[6], pl = P[7];
    const float sxi = P[8], syi = P[9];

    float* outp[4];
#pragma unroll
    for (int p = 0; p < 3; ++p) outp[p] = out + (size_t)(v * 3 + p) * HW;
    outp[3] = out + (size_t)(NV * 3) * HW + (size_t)v * HW;
    const size_t obase = (size_t)(ibase + il) * RES + y0b + 4 * q;

    // tile-level validity vs valid window [pl, pl+ow) x [pt, pt+oh)
    bool anyv = ((float)(x0b + 31) >= pl) && ((float)x0b < pl + owf) &&
                ((float)(y0b + 31) >= pt) && ((float)y0b < pt + ohf);
    if (!anyv) {
        f32x4 z4 = (f32x4)0.0f;
#pragma unroll
        for (int p = 0; p < 4; ++p)
            __builtin_nontemporal_store(z4, (f32x4*)(outp[p] + obase));
        return;
    }

    // per-thread x (S column) coords
    float xs = (float)(x0b + tx) - pl;
    bool vx = (xs >= 0.0f) && (xs < owf);
    float sx = fmaxf(__fadd_rn(__fmul_rn(__fadd_rn(xs, 0.5f), sxi), -0.5f), 0.0f);
    float flx = floorf(sx);
    float fx = sx - flx;
    float x0f = fminf(fmaxf(flx, 0.0f), wn - 1.0f);
    float x1f = fminf(x0f + 1.0f, wn - 1.0f);
    int gx0 = (int)(x0f + mw);
    int gx1 = (int)(x1f + mw);
    float nxf = fminf(fmaxf(floorf(__fmul_rn(xs, sxi)), 0.0f), wn - 1.0f);
    int gnx = (int)(nxf + mw);

    // per-thread y (S row) coords, 4 sub-rows
    int gy0[4], gy1[4], gny[4];
    float fy[4];
    bool vyk[4];
#pragma unroll
    for (int k = 0; k < 4; ++k) {
        float ysf = (float)(y0b + ty + 8 * k) - pt;
        vyk[k] = (ysf >= 0.0f) && (ysf < ohf);
        float sy = fmaxf(__fadd_rn(__fmul_rn(__fadd_rn(ysf, 0.5f), syi), -0.5f), 0.0f);
        float fly = floorf(sy);
        fy[k] = sy - fly;
        float y0f = fminf(fmaxf(fly, 0.0f), hn - 1.0f);
        float y1f = fminf(y0f + 1.0f, hn - 1.0f);
        gy0[k] = (int)(y0f + mh);
        gy1[k] = (int)(y1f + mh);
        float nyf = fminf(fmaxf(floorf(__fmul_rn(ysf, syi)), 0.0f), hn - 1.0f);
        gny[k] = (int)(nyf + mh);
    }

    __shared__ float tile[4][32][33];   // [plane][y_local][x_local]

#pragma unroll
    for (int p = 0; p < 3; ++p) {
        const float* img = rgbs + (size_t)(v * 3 + p) * HW;
        float omfx = 1.0f - fx;
#pragma unroll
        for (int k = 0; k < 4; ++k) {
            float val = 0.0f;
            if (vx & vyk[k]) {
                const float* r0 = img + gy0[k] * RES;
                const float* r1 = img + gy1[k] * RES;
                float a = r0[gx0], b = r0[gx1], c = r1[gx0], d = r1[gx1];
                float top = a * omfx + b * fx;
                float bot = c * omfx + d * fx;
                val = top * (1.0f - fy[k]) + bot * fy[k];
            }
            tile[p][ty + 8 * k][tx] = val;
        }
    }
    {
        const float* img = masks + (size_t)v * HW;
#pragma unroll
        for (int k = 0; k < 4; ++k)
            tile[3][ty + 8 * k][tx] = (vx & vyk[k]) ? img[gny[k] * RES + gnx] : 0.0f;
    }

    __syncthreads();

    const int xl = 31 - il;   // S x_local for this output row
#pragma unroll
    for (int p = 0; p < 4; ++p) {
        f32x4 w;
        w.x = tile[p][4 * q + 0][xl];
        w.y = tile[p][4 * q + 1][xl];
        w.z = tile[p][4 * q + 2][xl];
        w.w = tile[p][4 * q + 3][xl];
        __builtin_nontemporal_store(w, (f32x4*)(outp[p] + obase));
    }
}

extern "C" void kernel_launch(void* const* d_in, const int* in_sizes, int n_in,
                              void* d_out, int out_size, void* d_ws, size_t ws_size,
                              hipStream_t stream) {
    const float* rgbs  = (const float*)d_in[0];
    const float* masks = (const float*)d_in[1];
    const float* kc    = (const float*)d_in[2];
    float* out = (float*)d_out;
    int4* part    = (int4*)d_ws;                           // NV*256*16 = 32768 B
    int* cnt      = (int*)((char*)d_ws + 32768);           // NV*4 B
    float* params = (float*)((char*)d_ws + 33280);
    float* kc_out = out + (size_t)NV * 3 * HW + (size_t)NV * HW;   // offset 33554432

    hipMemsetAsync(cnt, 0, NV * sizeof(int), stream);
    bbox_params_kernel<<<dim3(256, NV), 256, 0, stream>>>(masks, kc, part, cnt, params, kc_out);
    resample_kernel<<<dim3(RES / 32, RES / 32, NV), 256, 0, stream>>>(
        rgbs, masks, params, out);
}

// Round 6
// 70.558 us; speedup vs baseline: 1.4564x; 1.4564x over previous
//
#include <hip/hip_runtime.h>

#define RES 1024
#define NV 8
#define HW (RES * RES)

typedef float f32x4 __attribute__((ext_vector_type(4)));

// ---------------------------------------------------------------- bbox partial scan
// 64 blocks per view; each block reduces its 4096-quad chunk into one int4 partial.
// No global atomics, no counters — partials consumed by resample prologue.
__global__ __launch_bounds__(256) void bbox_partial(const float* __restrict__ masks,
                                                    int4* __restrict__ part) {
    const int v = blockIdx.y;
    const int b = blockIdx.x;                 // 0..63
    const float4* m = (const float4*)(masks + (size_t)v * HW);
    int lminy = 1 << 30, lmaxy = -1, lminx = 1 << 30, lmaxx = -1;
    int base = b * 4096 + threadIdx.x;
#pragma unroll 4
    for (int i = 0; i < 16; ++i) {
        int q = base + i * 256;
        float4 f = m[q];
        bool a = f.x > 0.5f, bb = f.y > 0.5f, c = f.z > 0.5f, d = f.w > 0.5f;
        if (a | bb | c | d) {
            int lin = q << 2;
            int y = lin >> 10;
            int x = lin & (RES - 1);
            lminy = min(lminy, y); lmaxy = max(lmaxy, y);
            if (a)  { lminx = min(lminx, x);     lmaxx = max(lmaxx, x);     }
            if (bb) { lminx = min(lminx, x + 1); lmaxx = max(lmaxx, x + 1); }
            if (c)  { lminx = min(lminx, x + 2); lmaxx = max(lmaxx, x + 2); }
            if (d)  { lminx = min(lminx, x + 3); lmaxx = max(lmaxx, x + 3); }
        }
    }
    __shared__ int s[4];
    if (threadIdx.x == 0) { s[0] = 1 << 30; s[1] = -1; s[2] = 1 << 30; s[3] = -1; }
    __syncthreads();
    if (lmaxy >= 0) {
        atomicMin(&s[0], lminy); atomicMax(&s[1], lmaxy);
        atomicMin(&s[2], lminx); atomicMax(&s[3], lmaxx);
    }
    __syncthreads();
    if (threadIdx.x == 0) part[v * 64 + b] = make_int4(s[0], s[1], s[2], s[3]);
}

// ---------------------------------------------------------------- resample + rot90 (+params prologue)
// Prologue: wave 0 reduces the view's 64 bbox partials, lane 0 computes params
// into LDS (block (0,0) also writes kc_new). Then: pre-rotation sample S[v,c,y,x];
// output out[i,j] = S[j, RES-1-i]; 4 plane tiles in LDS; float4 NT stores.
__global__ __launch_bounds__(256) void resample_kernel(const float* __restrict__ rgbs,
                                                       const float* __restrict__ masks,
                                                       const int4* __restrict__ part,
                                                       const float* __restrict__ kc,
                                                       float* __restrict__ out,
                                                       float* __restrict__ kc_out) {
    const int v = blockIdx.z;
    const int x0b = blockIdx.x * 32;
    const int y0b = blockIdx.y * 32;
    const int t = threadIdx.x;        // 0..255
    const int tx = t & 31;            // x within S tile
    const int ty = t >> 5;            // 0..7
    const int il = t >> 3;            // output row within tile (epilogue)
    const int q  = t & 7;             // float4 group (epilogue)
    const int ibase = 992 - x0b;      // RES-1-(x0b+31)

    __shared__ float Pp[10];

    if (t < 64) {
        int4 p = part[v * 64 + t];
        int bminh = p.x, bmaxh = p.y, bminw = p.z, bmaxw = p.w;
#pragma unroll
        for (int o = 32; o; o >>= 1) {
            bminh = min(bminh, __shfl_down(bminh, o));
            bmaxh = max(bmaxh, __shfl_down(bmaxh, o));
            bminw = min(bminw, __shfl_down(bminw, o));
            bmaxw = max(bmaxw, __shfl_down(bmaxw, o));
        }
        if (t == 0) {
            if (bmaxh < 0) { bminh = 0; bmaxh = RES - 1; }   // empty-mask fallback
            if (bmaxw < 0) { bminw = 0; bmaxw = RES - 1; }
            float mh = (float)min(max(bminh - 100, 0), RES - 1);
            float Mh = (float)min(max(bmaxh + 100, 0), RES - 1);
            float mw = (float)min(max(bminw - 100, 0), RES - 1);
            float Mw = (float)min(max(bmaxw + 100, 0), RES - 1);
            float hn = Mh - mh, wn = Mw - mw;
            bool vert = (hn >= wn);
            float ohf = vert ? 1024.0f : floorf(__fdiv_rn(__fmul_rn(hn, 1024.0f), wn));
            float owf = vert ? floorf(__fdiv_rn(__fmul_rn(wn, 1024.0f), hn)) : 1024.0f;
            float ptp = floorf(__fmul_rn(1024.0f - ohf, 0.5f));
            float plp = floorf(__fmul_rn(1024.0f - owf, 0.5f));
            Pp[0] = mh; Pp[1] = mw; Pp[2] = hn; Pp[3] = wn;
            Pp[4] = ohf; Pp[5] = owf; Pp[6] = ptp; Pp[7] = plp;
            Pp[8] = __fdiv_rn(wn, owf);
            Pp[9] = __fdiv_rn(hn, ohf);
            if (x0b == 0 && y0b == 0) {
                // kc_new = R @ (A @ kc),  R = [[0,1,0],[-1,0,1024],[0,0,1]] (ROT_DEG==1)
                float axk = __fdiv_rn(owf, wn), ayk = __fdiv_rn(ohf, hn);
                float t0 = plp - mw * axk;
                float t1 = ptp - mh * ayk;
                const float* K = kc + v * 9;
                float* O = kc_out + v * 9;
#pragma unroll
                for (int k = 0; k < 3; ++k) {
                    float M0 = axk * K[k]     + t0 * K[6 + k];
                    float M1 = ayk * K[3 + k] + t1 * K[6 + k];
                    float M2 = K[6 + k];
                    O[k]     = M1;
                    O[3 + k] = -M0 + 1024.0f * M2;
                    O[6 + k] = M2;
                }
            }
        }
    }
    __syncthreads();

    const float mh = Pp[0], mw = Pp[1], hn = Pp[2], wn = Pp[3];
    const float ohf = Pp[4], owf = Pp[5], pt = Pp[6], pl = Pp[7];
    const float sxi = Pp[8], syi = Pp[9];

    float* outp[4];
#pragma unroll
    for (int p = 0; p < 3; ++p) outp[p] = out + (size_t)(v * 3 + p) * HW;
    outp[3] = out + (size_t)(NV * 3) * HW + (size_t)v * HW;
    const size_t obase = (size_t)(ibase + il) * RES + y0b + 4 * q;

    // tile-level validity vs valid window [pl, pl+ow) x [pt, pt+oh)
    bool anyv = ((float)(x0b + 31) >= pl) && ((float)x0b < pl + owf) &&
                ((float)(y0b + 31) >= pt) && ((float)y0b < pt + ohf);
    if (!anyv) {
        f32x4 z4 = (f32x4)0.0f;
#pragma unroll
        for (int p = 0; p < 4; ++p)
            __builtin_nontemporal_store(z4, (f32x4*)(outp[p] + obase));
        return;
    }

    // per-thread x (S column) coords
    float xs = (float)(x0b + tx) - pl;
    bool vx = (xs >= 0.0f) && (xs < owf);
    float sx = fmaxf(__fadd_rn(__fmul_rn(__fadd_rn(xs, 0.5f), sxi), -0.5f), 0.0f);
    float flx = floorf(sx);
    float fx = sx - flx;
    float x0f = fminf(fmaxf(flx, 0.0f), wn - 1.0f);
    float x1f = fminf(x0f + 1.0f, wn - 1.0f);
    int gx0 = (int)(x0f + mw);
    int gx1 = (int)(x1f + mw);
    float nxf = fminf(fmaxf(floorf(__fmul_rn(xs, sxi)), 0.0f), wn - 1.0f);
    int gnx = (int)(nxf + mw);

    // per-thread y (S row) coords, 4 sub-rows
    int gy0[4], gy1[4], gny[4];
    float fy[4];
    bool vyk[4];
#pragma unroll
    for (int k = 0; k < 4; ++k) {
        float ysf = (float)(y0b + ty + 8 * k) - pt;
        vyk[k] = (ysf >= 0.0f) && (ysf < ohf);
        float sy = fmaxf(__fadd_rn(__fmul_rn(__fadd_rn(ysf, 0.5f), syi), -0.5f), 0.0f);
        float fly = floorf(sy);
        fy[k] = sy - fly;
        float y0f = fminf(fmaxf(fly, 0.0f), hn - 1.0f);
        float y1f = fminf(y0f + 1.0f, hn - 1.0f);
        gy0[k] = (int)(y0f + mh);
        gy1[k] = (int)(y1f + mh);
        float nyf = fminf(fmaxf(floorf(__fmul_rn(ysf, syi)), 0.0f), hn - 1.0f);
        gny[k] = (int)(nyf + mh);
    }

    __shared__ float tile[4][32][33];   // [plane][y_local][x_local]

#pragma unroll
    for (int p = 0; p < 3; ++p) {
        const float* img = rgbs + (size_t)(v * 3 + p) * HW;
        float omfx = 1.0f - fx;
#pragma unroll
        for (int k = 0; k < 4; ++k) {
            float val = 0.0f;
            if (vx & vyk[k]) {
                const float* r0 = img + gy0[k] * RES;
                const float* r1 = img + gy1[k] * RES;
                float a = r0[gx0], b = r0[gx1], c = r1[gx0], d = r1[gx1];
                float top = a * omfx + b * fx;
                float bot = c * omfx + d * fx;
                val = top * (1.0f - fy[k]) + bot * fy[k];
            }
            tile[p][ty + 8 * k][tx] = val;
        }
    }
    {
        const float* img = masks + (size_t)v * HW;
#pragma unroll
        for (int k = 0; k < 4; ++k)
            tile[3][ty + 8 * k][tx] = (vx & vyk[k]) ? img[gny[k] * RES + gnx] : 0.0f;
    }

    __syncthreads();

    const int xl = 31 - il;   // S x_local for this output row
#pragma unroll
    for (int p = 0; p < 4; ++p) {
        f32x4 w;
        w.x = tile[p][4 * q + 0][xl];
        w.y = tile[p][4 * q + 1][xl];
        w.z = tile[p][4 * q + 2][xl];
        w.w = tile[p][4 * q + 3][xl];
        __builtin_nontemporal_store(w, (f32x4*)(outp[p] + obase));
    }
}

extern "C" void kernel_launch(void* const* d_in, const int* in_sizes, int n_in,
                              void* d_out, int out_size, void* d_ws, size_t ws_size,
                              hipStream_t stream) {
    const float* rgbs  = (const float*)d_in[0];
    const float* masks = (const float*)d_in[1];
    const float* kc    = (const float*)d_in[2];
    float* out = (float*)d_out;
    int4* part = (int4*)d_ws;                              // NV*64*16 = 8192 B
    float* kc_out = out + (size_t)NV * 3 * HW + (size_t)NV * HW;   // offset 33554432

    bbox_partial<<<dim3(64, NV), 256, 0, stream>>>(masks, part);
    resample_kernel<<<dim3(RES / 32, RES / 32, NV), 256, 0, stream>>>(
        rgbs, masks, part, kc, out, kc_out);
}